// Round 5
// baseline (146.080 us; speedup 1.0000x reference)
//
#include <hip/hip_runtime.h>

#define B_ 64
#define N_ 768
#define F_ 256
#define P_ 64
#define T_ 16
#define K_ 3
#define L_ 12            // N_/P_
#define C4_ 192          // float4 col groups per adj row (768/4)
#define PA_BLOCKS 576    // B_*L_*C4_ / 256
#define CONV_BLOCKS 768  // B_*L_
// ws layout (floats): sT[64][16] @0, sU[16][64] @1024, tmp[768][16][768] @2048
#define WS_NEED_BYTES (8192 + (size_t)B_ * L_ * T_ * N_ * 4)

// ---------------------------------------------------------------------------
// k0: s[t,p] = sum_k conv_w[t,p,k]*re[k]  -> sT[p][t] (for SMEM) + sU[u][p]
// ---------------------------------------------------------------------------
__global__ void compute_s_kernel(const float* __restrict__ conv_w,
                                 const float* __restrict__ re_param,
                                 float* __restrict__ ws) {
    const int j = blockIdx.x * 256 + threadIdx.x;
    if (j < P_ * T_) {
        const int p = j >> 4, t = j & 15;
        const float* w = conv_w + (size_t)t * (P_ * K_) + (size_t)p * K_;
        const float s = w[0] * re_param[0] + w[1] * re_param[1] + w[2] * re_param[2];
        ws[p * T_ + t] = s;          // sT
        ws[1024 + t * P_ + p] = s;   // sU
    }
}

// ---------------------------------------------------------------------------
// kA: fused streaming kernel, no LDS, no barriers.
//   blk < PA_BLOCKS: phase A. thread = (bl, c4): tmp[bl][t][4c4..] for all t.
//   else: conv role, one (b,l) per block, thread = f.
// ---------------------------------------------------------------------------
__global__ __launch_bounds__(256) void streamA_kernel(
    const float* __restrict__ x, const float* __restrict__ adj,
    const float* __restrict__ conv_w, const float* __restrict__ conv_b,
    const float* __restrict__ sT, float* __restrict__ tmp,
    float* __restrict__ out_x)
{
    const int blk = blockIdx.x;
    const int tid = threadIdx.x;

    if (blk < PA_BLOCKS) {
        const int j  = blk * 256 + tid;
        const int c4 = j % C4_;              // float4 col group 0..191
        const int bl = j / C4_;              // b*12 + l
        const float* arow = adj + (size_t)bl * (P_ * N_) + 4 * c4;

        float acc[T_][4];
        #pragma unroll
        for (int t = 0; t < T_; ++t) {
            acc[t][0] = 0.f; acc[t][1] = 0.f; acc[t][2] = 0.f; acc[t][3] = 0.f;
        }

        for (int p0 = 0; p0 < P_; p0 += 4) {
            float4 a[4];
            #pragma unroll
            for (int r = 0; r < 4; ++r)
                a[r] = *(const float4*)(arow + (size_t)(p0 + r) * N_);
            #pragma unroll
            for (int r = 0; r < 4; ++r) {
                const float* sp = sT + (p0 + r) * T_;   // thread-uniform -> s_load
                #pragma unroll
                for (int t = 0; t < T_; ++t) {
                    const float sv = sp[t];
                    acc[t][0] = fmaf(sv, a[r].x, acc[t][0]);
                    acc[t][1] = fmaf(sv, a[r].y, acc[t][1]);
                    acc[t][2] = fmaf(sv, a[r].z, acc[t][2]);
                    acc[t][3] = fmaf(sv, a[r].w, acc[t][3]);
                }
            }
        }
        float* trow = tmp + (size_t)bl * (T_ * N_) + 4 * c4;
        #pragma unroll
        for (int t = 0; t < T_; ++t) {
            float4 v;
            v.x = acc[t][0]; v.y = acc[t][1]; v.z = acc[t][2]; v.w = acc[t][3];
            *(float4*)(trow + (size_t)t * N_) = v;
        }
        return;
    }

    // ---------------- conv role ----------------
    const int idx = blk - PA_BLOCKS;
    const int b = idx / L_, l = idx % L_;
    const int f = tid;
    const float* xb = x + (size_t)b * N_ * F_ + (size_t)l * F_;

    float acc[T_];
    #pragma unroll
    for (int t = 0; t < T_; ++t) acc[t] = conv_b[t];

    for (int p0 = 0; p0 < P_; p0 += 2) {
        float xm[2], x0[2], xp[2];
        #pragma unroll
        for (int rr = 0; rr < 2; ++rr) {
            const float* row = xb + (size_t)(p0 + rr) * (L_ * F_);
            xm[rr] = (f > 0)      ? row[f - 1] : 0.f;
            x0[rr] = row[f];
            xp[rr] = (f < F_ - 1) ? row[f + 1] : 0.f;
        }
        #pragma unroll
        for (int rr = 0; rr < 2; ++rr) {
            const float* wp = conv_w + (p0 + rr) * K_;  // thread-uniform
            #pragma unroll
            for (int t = 0; t < T_; ++t) {
                const float w0 = wp[t * (P_ * K_) + 0];
                const float w1 = wp[t * (P_ * K_) + 1];
                const float w2 = wp[t * (P_ * K_) + 2];
                acc[t] = fmaf(xm[rr], w0, fmaf(x0[rr], w1, fmaf(xp[rr], w2, acc[t])));
            }
        }
    }
    float* ob = out_x + (size_t)b * (T_ * L_) * F_ + f;
    #pragma unroll
    for (int t = 0; t < T_; ++t)
        ob[(size_t)(t * L_ + l) * F_] = acc[t];
}

// ---------------------------------------------------------------------------
// kB: block = (bl, m), thread = (t,u):
//   out[b, l*16+t, m*16+u] = sum_q tmp[bl][t][m*64+q] * sU[u][q]
// tmp lines broadcast across the 16 u-lanes (L1-served); sU is globally hot.
// ---------------------------------------------------------------------------
__global__ __launch_bounds__(256) void streamB_kernel(
    const float* __restrict__ tmp, const float* __restrict__ sU,
    float* __restrict__ out_adj)
{
    const int blk = blockIdx.x;          // bl*12 + m
    const int m  = blk % L_;
    const int bl = blk / L_;
    const int t = threadIdx.x >> 4, u = threadIdx.x & 15;

    const float* trow = tmp + (size_t)bl * (T_ * N_) + (size_t)t * N_ + m * P_;
    const float* srow = sU + u * P_;

    float sum = 0.f;
    #pragma unroll
    for (int q4 = 0; q4 < P_; q4 += 4) {
        const float4 tv = *(const float4*)(trow + q4);
        const float4 sv = *(const float4*)(srow + q4);
        sum = fmaf(tv.x, sv.x, fmaf(tv.y, sv.y, fmaf(tv.z, sv.z, fmaf(tv.w, sv.w, sum))));
    }

    out_adj[((size_t)(bl / L_) * (L_ * T_) + (bl % L_) * T_ + t) * (L_ * T_)
            + m * T_ + u] = sum;
}

// ---------------------------------------------------------------------------
// Fallback (ws too small): R2's proven fused kernel (76 us).
// ---------------------------------------------------------------------------
#define TSTRIDE 772
__global__ __launch_bounds__(256) void fallback_fused_kernel(
    const float* __restrict__ x, const float* __restrict__ adj,
    const float* __restrict__ conv_w, const float* __restrict__ conv_b,
    const float* __restrict__ re_param,
    float* __restrict__ out_x, float* __restrict__ out_adj)
{
    __shared__ float sT[P_][T_];
    __shared__ float tmp[T_][TSTRIDE];

    const int blk  = blockIdx.x;
    const int role = blk & 1;
    const int idx  = blk >> 1;
    const int b = idx / L_, l = idx % L_;
    const int tid = threadIdx.x;

    if (role == 1) {
        const int f = tid;
        const float* xb = x + (size_t)b * N_ * F_ + (size_t)l * F_;
        float acc[T_];
        #pragma unroll
        for (int t = 0; t < T_; ++t) acc[t] = conv_b[t];
        for (int p = 0; p < P_; ++p) {
            const float* row = xb + (size_t)p * (L_ * F_);
            const float xm = (f > 0)      ? row[f - 1] : 0.f;
            const float x0 = row[f];
            const float xp = (f < F_ - 1) ? row[f + 1] : 0.f;
            const float* wp = conv_w + p * K_;
            #pragma unroll
            for (int t = 0; t < T_; ++t) {
                acc[t] = fmaf(xm, wp[t * (P_ * K_)],
                         fmaf(x0, wp[t * (P_ * K_) + 1],
                         fmaf(xp, wp[t * (P_ * K_) + 2], acc[t])));
            }
        }
        float* ob = out_x + (size_t)b * (T_ * L_) * F_ + f;
        #pragma unroll
        for (int t = 0; t < T_; ++t)
            ob[(size_t)(t * L_ + l) * F_] = acc[t];
        return;
    }

    const float r0 = re_param[0], r1 = re_param[1], r2 = re_param[2];
    for (int i = tid; i < P_ * T_; i += 256) {
        const int p = i >> 4, t = i & 15;
        const float* wv = conv_w + (size_t)t * (P_ * K_) + (size_t)p * K_;
        sT[p][t] = wv[0] * r0 + wv[1] * r1 + wv[2] * r2;
    }
    __syncthreads();

    const int w  = tid >> 6;
    const int ct = tid & 63;
    float acc[4][12];
    #pragma unroll
    for (int jj = 0; jj < 4; ++jj)
        #pragma unroll
        for (int c = 0; c < 12; ++c) acc[jj][c] = 0.f;

    const float* ab = adj + (size_t)b * N_ * N_ + (size_t)(l * P_) * N_;
    for (int p = 0; p < P_; ++p) {
        const float* row = ab + (size_t)p * N_;
        const float4 a0 = *(const float4*)&row[ct * 4];
        const float4 a1 = *(const float4*)&row[ct * 4 + 256];
        const float4 a2 = *(const float4*)&row[ct * 4 + 512];
        #pragma unroll
        for (int jj = 0; jj < 4; ++jj) {
            const float sv = sT[p][4 * w + jj];
            acc[jj][0]  = fmaf(sv, a0.x, acc[jj][0]);
            acc[jj][1]  = fmaf(sv, a0.y, acc[jj][1]);
            acc[jj][2]  = fmaf(sv, a0.z, acc[jj][2]);
            acc[jj][3]  = fmaf(sv, a0.w, acc[jj][3]);
            acc[jj][4]  = fmaf(sv, a1.x, acc[jj][4]);
            acc[jj][5]  = fmaf(sv, a1.y, acc[jj][5]);
            acc[jj][6]  = fmaf(sv, a1.z, acc[jj][6]);
            acc[jj][7]  = fmaf(sv, a1.w, acc[jj][7]);
            acc[jj][8]  = fmaf(sv, a2.x, acc[jj][8]);
            acc[jj][9]  = fmaf(sv, a2.y, acc[jj][9]);
            acc[jj][10] = fmaf(sv, a2.z, acc[jj][10]);
            acc[jj][11] = fmaf(sv, a2.w, acc[jj][11]);
        }
    }
    #pragma unroll
    for (int jj = 0; jj < 4; ++jj)
        #pragma unroll
        for (int i = 0; i < 3; ++i) {
            float4 v;
            v.x = acc[jj][i * 4 + 0]; v.y = acc[jj][i * 4 + 1];
            v.z = acc[jj][i * 4 + 2]; v.w = acc[jj][i * 4 + 3];
            *(float4*)&tmp[4 * w + jj][ct * 4 + i * 256] = v;
        }
    __syncthreads();

    const int t = tid >> 4, u = tid & 15;
    float sum[L_];
    #pragma unroll
    for (int mm = 0; mm < L_; ++mm) sum[mm] = 0.f;
    for (int q4 = 0; q4 < P_; q4 += 4) {
        const float s0 = sT[q4 + 0][u];
        const float s1 = sT[q4 + 1][u];
        const float s2 = sT[q4 + 2][u];
        const float s3 = sT[q4 + 3][u];
        #pragma unroll
        for (int mm = 0; mm < L_; ++mm) {
            const float4 tv = *(const float4*)&tmp[t][mm * P_ + q4];
            sum[mm] = fmaf(tv.x, s0, fmaf(tv.y, s1, fmaf(tv.z, s2, fmaf(tv.w, s3, sum[mm]))));
        }
    }
    float* ob = out_adj + (size_t)b * (L_ * T_) * (L_ * T_)
                        + (size_t)(l * T_ + t) * (L_ * T_) + u;
    #pragma unroll
    for (int mm = 0; mm < L_; ++mm)
        ob[mm * T_] = sum[mm];
}

// ---------------------------------------------------------------------------
extern "C" void kernel_launch(void* const* d_in, const int* in_sizes, int n_in,
                              void* d_out, int out_size, void* d_ws, size_t ws_size,
                              hipStream_t stream) {
    (void)in_sizes; (void)n_in; (void)out_size;
    const float* x        = (const float*)d_in[0];
    const float* adj      = (const float*)d_in[1];
    const float* conv_w   = (const float*)d_in[2];
    const float* conv_b   = (const float*)d_in[3];
    const float* re_param = (const float*)d_in[4];

    float* pooled_x   = (float*)d_out;
    float* pooled_adj = (float*)d_out + (size_t)B_ * (T_ * L_) * F_;

    if (ws_size >= WS_NEED_BYTES) {
        float* ws  = (float*)d_ws;
        float* sT  = ws;
        float* sU  = ws + 1024;
        float* tmp = ws + 2048;
        compute_s_kernel<<<4, 256, 0, stream>>>(conv_w, re_param, ws);
        streamA_kernel<<<PA_BLOCKS + CONV_BLOCKS, 256, 0, stream>>>(
            x, adj, conv_w, conv_b, sT, tmp, pooled_x);
        streamB_kernel<<<B_ * L_ * L_, 256, 0, stream>>>(tmp, sU, pooled_adj);
    } else {
        fallback_fused_kernel<<<B_ * L_ * 2, 256, 0, stream>>>(
            x, adj, conv_w, conv_b, re_param, pooled_x, pooled_adj);
    }
}

// Round 6
// 100.354 us; speedup vs baseline: 1.4556x; 1.4556x over previous
//
#include <hip/hip_runtime.h>

#define B_ 64
#define N_ 768
#define F_ 256
#define P_ 64
#define T_ 16
#define K_ 3
#define L_ 12
#define TSTR 772   // tmp row stride (dwords): 768+4, 16B-aligned, ==4 mod 32 banks

// ws layout (floats): sT[64][16] @0 (p-major), sU[16][64] @1024 (t-major)

__global__ void compute_s_kernel(const float* __restrict__ conv_w,
                                 const float* __restrict__ re_param,
                                 float* __restrict__ ws) {
    const int j = blockIdx.x * 256 + threadIdx.x;
    if (j < P_ * T_) {
        const int p = j >> 4, t = j & 15;
        const float* w = conv_w + (size_t)t * (P_ * K_) + (size_t)p * K_;
        const float s = w[0] * re_param[0] + w[1] * re_param[1] + w[2] * re_param[2];
        ws[p * T_ + t] = s;          // sT[p][t]
        ws[1024 + t * P_ + p] = s;   // sU[t][p]
    }
}

// grid: 1536 adj blocks + 768 conv blocks, 192 threads each.
// adj id encode: g = (bl&7) + 8*tg + 16*(bl>>3)  -> pair (tg0,tg1) 8 apart => same XCD.
__global__ __launch_bounds__(192, 5) void fused_kernel(
    const float* __restrict__ x, const float* __restrict__ adj,
    const float* __restrict__ conv_w, const float* __restrict__ conv_b,
    const float* __restrict__ ws,
    float* __restrict__ out_x, float* __restrict__ out_adj)
{
    __shared__ float sS[P_][8];      // 2 KB: sS[p][j] = s[8*tg+j][p]
    __shared__ float tmp[8][TSTR];   // 24.7 KB

    const int g = blockIdx.x;
    const int tid = threadIdx.x;

    if (g < 1536) {
        // ---------------- pooled_adj (8 t-rows of one (b,l)) ----------------
        const int r  = g & 7;
        const int h  = g >> 3;
        const int tg = h & 1;
        const int bl = r + 8 * (h >> 1);
        const int b = bl / L_, l = bl % L_;

        if (tid < 128) {  // stage sS from ws (coalesced, conflict-free)
            const int p = tid >> 1, hh = tid & 1;
            const float4 v = *(const float4*)(ws + p * T_ + 8 * tg + 4 * hh);
            *(float4*)&sS[p][4 * hh] = v;
        }
        __syncthreads();

        const int c4 = tid;  // float4 col group 0..191
        const float* arow = adj + (size_t)bl * (P_ * N_) + 4 * c4;

        float acc[8][4];
        #pragma unroll
        for (int j = 0; j < 8; ++j) {
            acc[j][0] = 0.f; acc[j][1] = 0.f; acc[j][2] = 0.f; acc[j][3] = 0.f;
        }

        for (int p0 = 0; p0 < P_; p0 += 8) {
            float4 a[8];  // 8 x 1KiB/wave loads in flight
            #pragma unroll
            for (int rr = 0; rr < 8; ++rr)
                a[rr] = *(const float4*)(arow + (size_t)(p0 + rr) * N_);
            #pragma unroll
            for (int rr = 0; rr < 8; ++rr) {
                const float4 s0 = *(const float4*)&sS[p0 + rr][0];  // broadcast
                const float4 s1 = *(const float4*)&sS[p0 + rr][4];
#define FMA4(J, SV) \
    acc[J][0] = fmaf(SV, a[rr].x, acc[J][0]); \
    acc[J][1] = fmaf(SV, a[rr].y, acc[J][1]); \
    acc[J][2] = fmaf(SV, a[rr].z, acc[J][2]); \
    acc[J][3] = fmaf(SV, a[rr].w, acc[J][3]);
                FMA4(0, s0.x) FMA4(1, s0.y) FMA4(2, s0.z) FMA4(3, s0.w)
                FMA4(4, s1.x) FMA4(5, s1.y) FMA4(6, s1.z) FMA4(7, s1.w)
#undef FMA4
            }
        }

        #pragma unroll
        for (int j = 0; j < 8; ++j) {
            float4 v;
            v.x = acc[j][0]; v.y = acc[j][1]; v.z = acc[j][2]; v.w = acc[j][3];
            *(float4*)&tmp[j][4 * c4] = v;   // consecutive lanes -> consecutive 16B
        }
        __syncthreads();

        // Phase B: thread (j,u), tid<128: out row l*16+8tg+j, cols m*16+u, m=0..11
        if (tid < 128) {
            const int j = tid >> 4, u = tid & 15;
            float4 su[16];  // sU row u -> 64 VGPR (acc regs are dead here)
            #pragma unroll
            for (int q4 = 0; q4 < 16; ++q4)
                su[q4] = *(const float4*)(ws + 1024 + u * P_ + 4 * q4);

            const int row = l * T_ + 8 * tg + j;
            float* ob = out_adj + (size_t)b * (L_ * T_) * (L_ * T_)
                                + (size_t)row * (L_ * T_) + u;
            for (int m = 0; m < L_; ++m) {
                float sum = 0.f;
                #pragma unroll
                for (int q4 = 0; q4 < 16; ++q4) {
                    const float4 tv = *(const float4*)&tmp[j][m * P_ + 4 * q4];  // broadcast
                    sum = fmaf(tv.x, su[q4].x, fmaf(tv.y, su[q4].y,
                          fmaf(tv.z, su[q4].z, fmaf(tv.w, su[q4].w, sum))));
                }
                ob[m * T_] = sum;
            }
        }
        return;
    }

    // ---------------- pooled_x (conv role) ----------------
    const int bl = g - 1536;
    const int b = bl / L_, l = bl % L_;
    const float* xb = x + (size_t)b * N_ * F_ + (size_t)l * F_;

    for (int f0 = 0; f0 < F_; f0 += 192) {
        const int f = f0 + tid;
        if (f < F_) {
            float acc[T_];
            #pragma unroll
            for (int t = 0; t < T_; ++t) acc[t] = conv_b[t];

            for (int p0 = 0; p0 < P_; p0 += 4) {
                float xm[4], x0[4], xp[4];  // 12 loads in flight
                #pragma unroll
                for (int rr = 0; rr < 4; ++rr) {
                    const float* row = xb + (size_t)(p0 + rr) * (L_ * F_);
                    xm[rr] = (f > 0)      ? row[f - 1] : 0.f;
                    x0[rr] = row[f];
                    xp[rr] = (f < F_ - 1) ? row[f + 1] : 0.f;
                }
                #pragma unroll
                for (int rr = 0; rr < 4; ++rr) {
                    const float* wp = conv_w + (p0 + rr) * K_;  // uniform -> s_load
                    #pragma unroll
                    for (int t = 0; t < T_; ++t) {
                        const float w0 = wp[t * (P_ * K_) + 0];
                        const float w1 = wp[t * (P_ * K_) + 1];
                        const float w2 = wp[t * (P_ * K_) + 2];
                        acc[t] = fmaf(xm[rr], w0, fmaf(x0[rr], w1, fmaf(xp[rr], w2, acc[t])));
                    }
                }
            }
            float* ob = out_x + (size_t)b * (T_ * L_) * F_ + f;
            #pragma unroll
            for (int t = 0; t < T_; ++t)
                ob[(size_t)(t * L_ + l) * F_] = acc[t];
        }
    }
}

// ---------------------------------------------------------------------------
extern "C" void kernel_launch(void* const* d_in, const int* in_sizes, int n_in,
                              void* d_out, int out_size, void* d_ws, size_t ws_size,
                              hipStream_t stream) {
    (void)in_sizes; (void)n_in; (void)out_size; (void)ws_size;
    const float* x        = (const float*)d_in[0];
    const float* adj      = (const float*)d_in[1];
    const float* conv_w   = (const float*)d_in[2];
    const float* conv_b   = (const float*)d_in[3];
    const float* re_param = (const float*)d_in[4];

    float* pooled_x   = (float*)d_out;
    float* pooled_adj = (float*)d_out + (size_t)B_ * (T_ * L_) * F_;
    float* ws         = (float*)d_ws;   // needs 8 KB

    compute_s_kernel<<<4, 256, 0, stream>>>(conv_w, re_param, ws);
    fused_kernel<<<1536 + 768, 192, 0, stream>>>(
        x, adj, conv_w, conv_b, ws, pooled_x, pooled_adj);
}

// Round 7
// 78.766 us; speedup vs baseline: 1.8546x; 1.2741x over previous
//
#include <hip/hip_runtime.h>

#define B_ 64
#define N_ 768
#define F_ 256
#define P_ 64
#define T_ 16
#define K_ 3
#define L_ 12
#define TSTR 770   // tmp row stride (dwords): 768+2; keeps total LDS at 53,376 B

// Fused kernel, grid = 1536 blocks of 256 threads, role = blk&1.
// adj role: wave w owns t in [4w,4w+4); every wave loads the full 768-col
// stripe (4x redundant, L1-absorbed). Phase A->B via LDS tmp + barrier.
__global__ __launch_bounds__(256, 3) void fused_pool_kernel(
    const float* __restrict__ x, const float* __restrict__ adj,
    const float* __restrict__ conv_w, const float* __restrict__ conv_b,
    const float* __restrict__ re_param,
    float* __restrict__ out_x, float* __restrict__ out_adj)
{
    __shared__ float sT[P_][T_];     // 4 KB: sT[p][t] = s[t,p]
    __shared__ float tmp[T_][TSTR];  // 49.28 KB

    const int blk  = blockIdx.x;
    const int role = blk & 1;
    const int idx  = blk >> 1;
    const int b = idx / L_, l = idx % L_;
    const int tid = threadIdx.x;

    if (role == 1) {
        // ---------------- pooled_x ----------------
        const int f = tid;
        const float* xb = x + (size_t)b * N_ * F_ + (size_t)l * F_;
        float acc[T_];
        #pragma unroll
        for (int t = 0; t < T_; ++t) acc[t] = conv_b[t];
        for (int p = 0; p < P_; ++p) {
            const float* row = xb + (size_t)p * (L_ * F_);
            const float xm = (f > 0)      ? row[f - 1] : 0.f;
            const float x0 = row[f];
            const float xp = (f < F_ - 1) ? row[f + 1] : 0.f;
            const float* wp = conv_w + p * K_;   // thread-uniform -> s_load
            #pragma unroll
            for (int t = 0; t < T_; ++t) {
                acc[t] = fmaf(xm, wp[t * (P_ * K_)],
                         fmaf(x0, wp[t * (P_ * K_) + 1],
                         fmaf(xp, wp[t * (P_ * K_) + 2], acc[t])));
            }
        }
        float* ob = out_x + (size_t)b * (T_ * L_) * F_ + f;
        #pragma unroll
        for (int t = 0; t < T_; ++t)
            ob[(size_t)(t * L_ + l) * F_] = acc[t];
        return;
    }

    // ---------------- pooled_adj ----------------
    // s[t,p] = sum_k conv_w[t,p,k] * re_param[k]
    const float r0 = re_param[0], r1 = re_param[1], r2 = re_param[2];
    for (int i = tid; i < P_ * T_; i += 256) {
        const int p = i >> 4, t = i & 15;
        const float* wv = conv_w + (size_t)t * (P_ * K_) + (size_t)p * K_;
        sT[p][t] = wv[0] * r0 + wv[1] * r1 + wv[2] * r2;
    }
    __syncthreads();

    // Phase A, software-pipelined: prefetch p+1 while computing p.
    const int w  = tid >> 6;
    const int ct = tid & 63;
    const int c4 = ct * 4;

    float acc[4][12];
    #pragma unroll
    for (int j = 0; j < 4; ++j)
        #pragma unroll
        for (int c = 0; c < 12; ++c) acc[j][c] = 0.f;

    const float* ab = adj + (size_t)b * N_ * N_ + (size_t)(l * P_) * N_;

    float4 c0 = *(const float4*)&ab[c4];
    float4 c1 = *(const float4*)&ab[c4 + 256];
    float4 c2 = *(const float4*)&ab[c4 + 512];

    #pragma unroll 2
    for (int p = 0; p < P_; ++p) {
        const int pn = (p < P_ - 1) ? p + 1 : p;   // clamp: stay in this block's rows
        const float* nrow = ab + (size_t)pn * N_;
        const float4 n0 = *(const float4*)&nrow[c4];
        const float4 n1 = *(const float4*)&nrow[c4 + 256];
        const float4 n2 = *(const float4*)&nrow[c4 + 512];

        const float4 sv = *(const float4*)&sT[p][4 * w];  // wave-uniform b128 broadcast
#define FMA12(J, S) \
        acc[J][0]  = fmaf(S, c0.x, acc[J][0]);  \
        acc[J][1]  = fmaf(S, c0.y, acc[J][1]);  \
        acc[J][2]  = fmaf(S, c0.z, acc[J][2]);  \
        acc[J][3]  = fmaf(S, c0.w, acc[J][3]);  \
        acc[J][4]  = fmaf(S, c1.x, acc[J][4]);  \
        acc[J][5]  = fmaf(S, c1.y, acc[J][5]);  \
        acc[J][6]  = fmaf(S, c1.z, acc[J][6]);  \
        acc[J][7]  = fmaf(S, c1.w, acc[J][7]);  \
        acc[J][8]  = fmaf(S, c2.x, acc[J][8]);  \
        acc[J][9]  = fmaf(S, c2.y, acc[J][9]);  \
        acc[J][10] = fmaf(S, c2.z, acc[J][10]); \
        acc[J][11] = fmaf(S, c2.w, acc[J][11]);
        FMA12(0, sv.x)
        FMA12(1, sv.y)
        FMA12(2, sv.z)
        FMA12(3, sv.w)
#undef FMA12
        c0 = n0; c1 = n1; c2 = n2;
    }

    #pragma unroll
    for (int j = 0; j < 4; ++j) {
        #pragma unroll
        for (int i = 0; i < 3; ++i) {
            float4 v;
            v.x = acc[j][i * 4 + 0]; v.y = acc[j][i * 4 + 1];
            v.z = acc[j][i * 4 + 2]; v.w = acc[j][i * 4 + 3];
            *(float4*)&tmp[4 * w + j][c4 + i * 256] = v;
        }
    }
    __syncthreads();

    // Phase B: out[b, l*T+t, m*T+u] = sum_q tmp[t][m*64+q] * sT[q][u]
    const int t = tid >> 4, u = tid & 15;
    float sum[L_];
    #pragma unroll
    for (int m = 0; m < L_; ++m) sum[m] = 0.f;

    for (int q4 = 0; q4 < P_; q4 += 4) {
        const float s0 = sT[q4 + 0][u];
        const float s1 = sT[q4 + 1][u];
        const float s2 = sT[q4 + 2][u];
        const float s3 = sT[q4 + 3][u];
        #pragma unroll
        for (int m = 0; m < L_; ++m) {
            const float4 tv = *(const float4*)&tmp[t][m * P_ + q4];  // 16-lane broadcast
            sum[m] = fmaf(tv.x, s0, fmaf(tv.y, s1, fmaf(tv.z, s2, fmaf(tv.w, s3, sum[m]))));
        }
    }

    float* ob = out_adj + (size_t)b * (L_ * T_) * (L_ * T_)
                        + (size_t)(l * T_ + t) * (L_ * T_) + u;
    #pragma unroll
    for (int m = 0; m < L_; ++m)
        ob[m * T_] = sum[m];
}

// ---------------------------------------------------------------------------
extern "C" void kernel_launch(void* const* d_in, const int* in_sizes, int n_in,
                              void* d_out, int out_size, void* d_ws, size_t ws_size,
                              hipStream_t stream) {
    (void)in_sizes; (void)n_in; (void)out_size; (void)d_ws; (void)ws_size;
    const float* x        = (const float*)d_in[0];
    const float* adj      = (const float*)d_in[1];
    const float* conv_w   = (const float*)d_in[2];
    const float* conv_b   = (const float*)d_in[3];
    const float* re_param = (const float*)d_in[4];

    float* pooled_x   = (float*)d_out;
    float* pooled_adj = (float*)d_out + (size_t)B_ * (T_ * L_) * F_;

    fused_pool_kernel<<<B_ * L_ * 2, 256, 0, stream>>>(
        x, adj, conv_w, conv_b, re_param, pooled_x, pooled_adj);
}